// Round 1
// baseline (50.703 us; speedup 1.0000x reference)
//
#include <hip/hip_runtime.h>

// Problem: out[r][c] = in[r][c] * weight[c][c] + bias[c]
// B = 8192 rows, N = 4096 cols, all float32.
// Pure memory-bound elementwise op: ~128 MiB read + ~128 MiB write.

#define NCOL 4096
#define NROW 8192

__global__ __launch_bounds__(256)
void extract_diag_kernel(const float* __restrict__ w, float* __restrict__ d) {
    int i = blockIdx.x * blockDim.x + threadIdx.x;
    if (i < NCOL) {
        d[i] = w[(size_t)i * NCOL + i];
    }
}

__global__ __launch_bounds__(256)
void scale_bias_kernel(const float4* __restrict__ in,
                       const float4* __restrict__ diag4,
                       const float4* __restrict__ bias4,
                       float4* __restrict__ out,
                       long total4) {
    const long stride = (long)gridDim.x * blockDim.x;
    for (long i = (long)blockIdx.x * blockDim.x + threadIdx.x; i < total4; i += stride) {
        const int j = (int)(i & (NCOL / 4 - 1));   // column quad index within row
        const float4 x = in[i];
        const float4 d = diag4[j];
        const float4 b = bias4[j];
        float4 o;
        o.x = fmaf(x.x, d.x, b.x);
        o.y = fmaf(x.y, d.y, b.y);
        o.z = fmaf(x.z, d.z, b.z);
        o.w = fmaf(x.w, d.w, b.w);
        out[i] = o;
    }
}

extern "C" void kernel_launch(void* const* d_in, const int* in_sizes, int n_in,
                              void* d_out, int out_size, void* d_ws, size_t ws_size,
                              hipStream_t stream) {
    const float* input  = (const float*)d_in[0];
    const float* weight = (const float*)d_in[1];
    const float* bias   = (const float*)d_in[2];
    float* out  = (float*)d_out;
    float* diag = (float*)d_ws;   // 4096 floats = 16 KiB scratch

    // 1) extract diagonal of weight into workspace
    extract_diag_kernel<<<(NCOL + 255) / 256, 256, 0, stream>>>(weight, diag);

    // 2) vectorized elementwise scale + bias
    const long total4 = (long)NROW * NCOL / 4;   // 8,388,608 float4s
    const int block = 256;
    const int grid = 2048;                        // grid-stride; 256 CU x 8 blocks
    scale_bias_kernel<<<grid, block, 0, stream>>>(
        (const float4*)input, (const float4*)diag, (const float4*)bias,
        (float4*)out, total4);
}